// Round 9
// baseline (215.168 us; speedup 1.0000x reference)
//
#include <hip/hip_runtime.h>
#include <math.h>

#define HH 192
#define WW 192
#define CC 64
#define CHW (HH*WW)
#define SS 16
#define NB 12
#define NBLK 144
#define NSH 49
#define UROW 22          // union region rows
#define RW 24            // region row elems staged (16B-aligned from cbase4)
#define RDW 13           // dwords per packed bf16 copy-row (12 data + 1 pad)
#define NCHK 2           // channels per MFMA K-step
#define NT 10            // N-tiles of 16 covering 154 (yw,u) columns
#define LN 160           // S row stride
#define CSTRIDE (UROW*2*RDW)   // 572 dw per channel in region slice
#define REGDW (NCHK*CSTRIDE)   // 1144 dw region per wave
// overlay offsets (dwords; valid after region is dead)
#define S0   0
#define RS0  (16*LN)           // 2560
#define CS0  (RS0 + UROW*RW)   // 3088
#define ASUM0 (CS0 + 154)      // 3242
#define OVL_N (ASUM0 + 1)
#define LDS_DW (4*REGDW)       // 4576 dwords = 18304 B

typedef __attribute__((ext_vector_type(4))) float f32x4;
typedef __attribute__((ext_vector_type(8))) short bf16x8;

__device__ __forceinline__ int iclamp(int v, int lo, int hi){ return v<lo?lo:(v>hi?hi:v); }

__device__ __forceinline__ unsigned f2bf(float f){
  unsigned u = __float_as_uint(f);
  return (u + 0x7FFFu + ((u >> 16) & 1u)) >> 16;
}
__device__ __forceinline__ unsigned pk2(float lo, float hi){
  return f2bf(lo) | (f2bf(hi) << 16);
}

// NZ: channel split; 1D grid with XCD-pinned raster swizzle (b = wg&7 fixed per XCD)
template<int NZ>
__global__ __launch_bounds__(256, 4) void dist_kernel(
    const float* __restrict__ fm1, const float* __restrict__ fm2,
    float* __restrict__ partial)
{
  __shared__ unsigned smu[LDS_DW];
  float* smf = (float*)smu;

  const int wg  = blockIdx.x;           // [0, NZ*1152)
  const int z   = (NZ == 2 && wg >= 8*NBLK) ? 1 : 0;
  const int w2  = wg - z*8*NBLK;
  const int b   = w2 & 7;               // batch pinned per XCD
  const int blk = w2 >> 3;              // 0..143 raster (halo L2 reuse)
  const int by  = blk / NB, bx = blk - by*NB;
  const int ys  = by*SS, xs = bx*SS;
  const int rbase = iclamp(ys-3, 0, HH-UROW);
  const int ey = (ys-3) - rbase;
  const int cbase  = iclamp(xs-3, 0, WW-UROW);
  const int cbase4 = (bx == 0) ? 0 : ((bx == NB-1) ? (WW-RW) : (xs-4));
  const int OX = cbase - cbase4;        // 0/1/2
  const int ex = (xs-3) - cbase;        // -3/0/3

  const int tid  = threadIdx.x;
  const int wid  = tid >> 6;
  const int lane = tid & 63;
  const int row16 = lane & 15;          // A: y row / B: n within tile
  const int kb    = lane >> 4;          // 0..3 k-block
  const int coff  = lane >> 5;          // channel within K-step (0..1)
  const int x0    = ((lane >> 4) & 1) * 8;

  const int NCHUNK = (CC/NZ)/4/NCHK;    // 4 (NZ=2) or 8 (NZ=1)
  const int c0w = z*(CC/NZ) + wid*(NCHK*NCHUNK);
  const int regbase = wid * REGDW;

  const float* f1b = fm1 + (size_t)b*CC*CHW;
  const float* f2b = fm2 + (size_t)b*CC*CHW;

  // ---- per-lane B-fragment LDS dword bases per N-tile (chunk-invariant)
  int boff[NT];
#pragma unroll
  for (int nt = 0; nt < NT; ++nt) {
    int n  = nt*16 + row16;
    int n7 = n / 7;
    int o  = n - n7*7;
    int yw = n7 > (UROW-1) ? (UROW-1) : n7;
    int e  = OX + o + x0;
    int p  = e & 1;
    int d0 = (e - p) >> 1;
    boff[nt] = regbase + ((coff*UROW + yw)*2 + p)*RDW + d0;
  }

  // ---- staging position assignment (static; 264 float2-pairs per channel)
  int pyw[5], pdp[5];
#pragma unroll
  for (int i = 0; i < 5; ++i) {
    int pi = lane + 64*i;
    int piq = (pi < 264) ? pi : 0;
    pyw[i] = piq / 12;
    pdp[i] = piq - 12*pyw[i];
  }
  const int aoff = (ys + row16)*WW + xs + x0;

  f32x4 acc[NT];
#pragma unroll
  for (int nt = 0; nt < NT; ++nt) acc[nt] = (f32x4){0.f,0.f,0.f,0.f};
  float rsa[5] = {0.f,0.f,0.f,0.f,0.f};
  float rsb[5] = {0.f,0.f,0.f,0.f,0.f};
  float asum = 0.f;

  // ================= main chunk loop (wave-private region, no barriers) ====
  for (int ck = 0; ck < NCHUNK; ++ck) {
    // ---- A fragment loads first (independent; overlaps staging latency)
    const float* ap = f1b + (size_t)(c0w + ck*NCHK + coff)*CHW + aoff;
    float4 a0 = *(const float4*)ap;
    float4 a1 = *(const float4*)(ap + 4);

    // ---- stage 2 channels of 22x24 region as 2 parity-packed bf16 copies
    const float* f2c = f2b + (size_t)(c0w + ck*NCHK)*CHW;
#pragma unroll
    for (int i = 0; i < 5; ++i) {
      if (i < 4 || lane < 8) {
        const int go = (rbase + pyw[i])*WW + cbase4 + 2*pdp[i];
        const int wo = regbase + (pyw[i]*2)*RDW + pdp[i];
        const bool has2 = (pdp[i] < 11);
#pragma unroll
        for (int ch = 0; ch < NCHK; ++ch) {
          const float* g = f2c + (size_t)ch*CHW + go;
          float2 v01 = *(const float2*)g;
          float e2 = has2 ? g[2] : 0.f;
          smu[wo + ch*CSTRIDE]       = pk2(v01.x, v01.y);  // elems (2d,2d+1)
          smu[wo + ch*CSTRIDE + RDW] = pk2(v01.y, e2);     // elems (2d+1,2d+2)
          rsa[i] = fmaf(v01.x, v01.x, rsa[i]);
          rsb[i] = fmaf(v01.y, v01.y, rsb[i]);
        }
      }
    }

    // ---- finish A fragment (pack + a^2)
    asum = fmaf(a0.x,a0.x, fmaf(a0.y,a0.y, fmaf(a0.z,a0.z, fmaf(a0.w,a0.w, asum))));
    asum = fmaf(a1.x,a1.x, fmaf(a1.y,a1.y, fmaf(a1.z,a1.z, fmaf(a1.w,a1.w, asum))));
    union { unsigned u[4]; bf16x8 v; } A_;
    A_.u[0] = pk2(a0.x, a0.y); A_.u[1] = pk2(a0.z, a0.w);
    A_.u[2] = pk2(a1.x, a1.y); A_.u[3] = pk2(a1.z, a1.w);

    // ---- 10 N-tiles, one K-step each (compiler inserts lgkmcnt for LDS dep)
#pragma unroll
    for (int nt = 0; nt < NT; ++nt) {
      const unsigned* bp = smu + boff[nt];
      union { unsigned u[4]; bf16x8 v; } B_;
      B_.u[0] = bp[0]; B_.u[1] = bp[1]; B_.u[2] = bp[2]; B_.u[3] = bp[3];
      acc[nt] = __builtin_amdgcn_mfma_f32_16x16x32_bf16(A_.v, B_.v, acc[nt], 0, 0, 0);
    }
  }

  // ================= merge phase ==========================================
  __syncthreads();                       // region dead; overlay S/RS/CS
  for (int i = tid; i < OVL_N; i += 256) smf[i] = 0.f;
  __syncthreads();

  // S[y][n] merge: C layout col=lane&15 (n), row=(lane>>4)*4+reg (y)
#pragma unroll
  for (int nt = 0; nt < NT; ++nt) {
#pragma unroll
    for (int r = 0; r < 4; ++r) {
      atomicAdd(&smf[S0 + (kb*4 + r)*LN + nt*16 + row16], acc[nt][r]);
    }
  }
  // RS merge (sum over this WG's channels of w^2 per region position)
#pragma unroll
  for (int i = 0; i < 5; ++i) {
    if (i < 4 || lane < 8) {
      atomicAdd(&smf[RS0 + pyw[i]*RW + 2*pdp[i]    ], rsa[i]);
      atomicAdd(&smf[RS0 + pyw[i]*RW + 2*pdp[i] + 1], rsb[i]);
    }
  }
  {
    float v = asum;
#pragma unroll
    for (int off = 32; off; off >>= 1) v += __shfl_xor(v, off);
    if (lane == 0) atomicAdd(&smf[ASUM0], v);
  }
  __syncthreads();

  // ---- CS[yw][o]: sliding 16-window sums of RS along x
  if (tid < 154) {
    int yw = tid / 7, o = tid - 7*yw;
    float s = 0.f;
#pragma unroll
    for (int x = 0; x < 16; ++x) s += smf[RS0 + yw*RW + OX + o + x];
    smf[CS0 + tid] = s;
  }
  __syncthreads();

  // ---- z-partial distances (49 values)
  if constexpr (NZ == 2) {
    if (tid < NSH) {
      int t = tid / 7, u = tid - 7*t;
      int oyt = iclamp(t + ey, 0, 6);
      int o   = iclamp(u + ex, 0, 6);
      float s = smf[ASUM0];
#pragma unroll
      for (int y = 0; y < 16; ++y) {
        int n = (y + oyt)*7 + o;
        s += smf[CS0 + n] - 2.f*smf[S0 + y*LN + n];
      }
      partial[((size_t)(b*NBLK + blk)*2 + z)*NSH + tid] = s;   // raw z-partial
    }
  } else {
    if (tid < 64) {
      int tu = tid < NSH ? tid : NSH-1;
      int t = tu / 7, u = tu - 7*t;
      int oyt = iclamp(t + ey, 0, 6);
      int o   = iclamp(u + ex, 0, 6);
      float s = smf[ASUM0];
#pragma unroll
      for (int y = 0; y < 16; ++y) {
        int n = (y + oyt)*7 + o;
        s += smf[CS0 + n] - 2.f*smf[S0 + y*LN + n];
      }
#pragma unroll
      for (int off = 32; off; off >>= 1) s = fminf(s, __shfl_xor(s, off));
      if (tid == 0) partial[(size_t)b*NBLK + blk] = s;         // raw min
    }
  }
}

template<int NZ>
__global__ void topk_kernel(const float* __restrict__ partial, float* __restrict__ out)
{
  const int b = blockIdx.x;            // 0..7
  const int lane = threadIdx.x;        // 0..63
  const float INF = __builtin_inff();

  float v0 = INF, v1 = INF, v2 = INF;
  if constexpr (NZ == 2) {
#pragma unroll
    for (int i = 0; i < 3; i++) {
      int blk = lane + 64*i;
      if (blk < NBLK) {
        const float* p = partial + (size_t)(b*NBLK + blk)*2*NSH;
        float m = INF;
        for (int k = 0; k < NSH; k++) m = fminf(m, p[k] + p[k+NSH]);
        if (i == 0) v0 = m; else if (i == 1) v1 = m; else v2 = m;
      }
    }
  } else {
    const float* p = partial + (size_t)b*NBLK;
    v0 = p[lane];
    v1 = p[lane + 64];
    v2 = (lane < 16) ? p[lane + 128] : INF;
  }

  float sum = 0.f;
  for (int it = 0; it < 16; ++it) {
    float lm = fminf(v0, fminf(v1, v2));
    float m = lm;
#pragma unroll
    for (int off = 32; off; off >>= 1) m = fminf(m, __shfl_xor(m, off));
    sum += m;
    unsigned long long mask = __ballot(lm == m);
    int leader = __ffsll(mask) - 1;
    if (lane == leader) {
      if (v0 == m)      v0 = INF;
      else if (v1 == m) v1 = INF;
      else              v2 = INF;
    }
  }
  if (lane == 0) out[b] = sum * (1.0f/((float)CC*SS*SS));
}

extern "C" void kernel_launch(void* const* d_in, const int* in_sizes, int n_in,
                              void* d_out, int out_size, void* d_ws, size_t ws_size,
                              hipStream_t stream)
{
  const float* fm1 = (const float*)d_in[0];
  const float* fm2 = (const float*)d_in[1];
  float* out  = (float*)d_out;
  float* scratch = (float*)d_ws;

  const size_t NEED = (size_t)8 * NBLK * 2 * NSH * sizeof(float);  // 451,584 B
  if (ws_size >= NEED) {
    dist_kernel<2><<<2*8*NBLK, 256, 0, stream>>>(fm1, fm2, scratch);
    topk_kernel<2><<<8, 64, 0, stream>>>(scratch, out);
  } else {
    dist_kernel<1><<<8*NBLK, 256, 0, stream>>>(fm1, fm2, scratch);
    topk_kernel<1><<<8, 64, 0, stream>>>(scratch, out);
  }
}

// Round 10
// 127.484 us; speedup vs baseline: 1.6878x; 1.6878x over previous
//
#include <hip/hip_runtime.h>
#include <math.h>

#define HH 192
#define WW 192
#define CC 64
#define CHW (HH*WW)
#define SS 16
#define NB 12
#define NBLK 144
#define NSH 49
#define UROW 22
#define RW 24                 // region row elems staged (16B-aligned from cbase4)
#define RDW 14                // dwords per packed copy-row (12 data + 2 pad; keeps b64 align)
#define CSTR (UROW*2*RDW)     // 616 dw per channel
#define BUFDW (8*CSTR)        // 4928 dw per 8-channel buffer
#define LDS_DW (2*BUFDW)      // 9856 dw = 39424 B (double buffer)
#define LN 160                // S row stride
#define S0 0
#define RS0 (16*LN)           // 2560
#define CS0 (RS0 + UROW*RW)   // 3088
#define ASUM0 (CS0 + 154)     // 3242
#define OVL_END (ASUM0 + 1)   // 3243 (< LDS_DW)
#define NSLOT 1056            // 8ch * 22r * 6q float4 slots per chunk

typedef __attribute__((ext_vector_type(4))) float f32x4;
typedef __attribute__((ext_vector_type(8))) short bf16x8;

__device__ __forceinline__ int iclamp(int v, int lo, int hi){ return v<lo?lo:(v>hi?hi:v); }

__device__ __forceinline__ unsigned f2bf(float f){
  unsigned u = __float_as_uint(f);
  return (u + 0x7FFFu + ((u >> 16) & 1u)) >> 16;
}
__device__ __forceinline__ unsigned pk2(float lo, float hi){
  return f2bf(lo) | (f2bf(hi) << 16);
}

// NZ: channel split; 1D grid, XCD-pinned raster swizzle (b = wg&7 fixed per XCD)
template<int NZ>
__global__ __launch_bounds__(256, 2) void dist_kernel(
    const float* __restrict__ fm1, const float* __restrict__ fm2,
    float* __restrict__ partial)
{
  __shared__ unsigned smu[LDS_DW];
  float* smf = (float*)smu;

  const int wg  = blockIdx.x;           // [0, NZ*1152)
  const int z   = (NZ == 2 && wg >= 8*NBLK) ? 1 : 0;
  const int w2  = wg - z*8*NBLK;
  const int b   = w2 & 7;
  const int blk = w2 >> 3;
  const int by  = blk / NB, bx = blk - by*NB;
  const int ys  = by*SS, xs = bx*SS;
  const int rbase = iclamp(ys-3, 0, HH-UROW);
  const int ey = (ys-3) - rbase;
  const int cbase  = iclamp(xs-3, 0, WW-UROW);
  const int cbase4 = (bx == 0) ? 0 : ((bx == NB-1) ? (WW-RW) : (xs-4));
  const int OX = cbase - cbase4;        // 0/1/2
  const int ex = (xs-3) - cbase;        // -3/0/3

  const int tid  = threadIdx.x;
  const int wid  = tid >> 6;
  const int lane = tid & 63;
  const int row16 = lane & 15;          // A: y row / B: n within tile
  const int kb    = lane >> 4;          // 0..3 k-block (C/D row group)
  const int coff  = lane >> 5;          // channel within K-step (0..1)
  const int x0    = ((lane >> 4) & 1) * 8;

  const int NCHUNK = (CC/NZ)/8;         // 4 (NZ=2) or 8 (NZ=1)
  const int cc0 = z*(CC/NZ);

  const float* f1b = fm1 + (size_t)b*CC*CHW;
  const float* f2b = fm2 + (size_t)b*CC*CHW;

  // ---- N-split: wave tiles {3,3,2,2} over 10 N-tiles
  const int tstart = (wid < 2) ? 3*wid : 2*wid + 2;   // 0,3,6,8
  const int tcnt   = (wid < 2) ? 3 : 2;
  int boffb[3];
#pragma unroll
  for (int j = 0; j < 3; ++j) {
    int nt = tstart + ((j < 3) ? j : 0); nt = nt > 9 ? 9 : nt;
    int n  = nt*16 + row16;
    int n7 = n / 7;
    int o  = n - n7*7;
    int yw = n7 > (UROW-1) ? (UROW-1) : n7;
    int e  = OX + o + x0;
    int p  = e & 1;
    int d0 = (e - p) >> 1;
    boffb[j] = (2*yw + p)*RDW + d0;     // + channel*CSTR + bufbase at use
  }

  // ---- staging slots (float4 granularity, 1056 slots per chunk)
  int goff[5], wo0[5], rpos[5];
  bool qlt5[5], valid[5];
#pragma unroll
  for (int j = 0; j < 5; ++j) {
    int i = tid + 256*j;
    valid[j] = (i < NSLOT);
    int iq = valid[j] ? i : 0;
    int ch = iq / 132;
    int rem = iq - 132*ch;
    int r  = rem / 6;
    int q  = rem - 6*r;
    goff[j] = ch*CHW + (rbase + r)*WW + cbase4 + 4*q;
    wo0[j]  = ch*CSTR + 28*r + 2*q;     // copy0 b64 base (even dword)
    rpos[j] = r*RW + 4*q;
    qlt5[j] = (q < 5);
  }
  const int aoff = (ys + row16)*WW + xs + x0;

  f32x4 acc[3];
#pragma unroll
  for (int j = 0; j < 3; ++j) acc[j] = (f32x4){0.f,0.f,0.f,0.f};
  float rs[5][4];
#pragma unroll
  for (int j = 0; j < 5; ++j) { rs[j][0]=0.f; rs[j][1]=0.f; rs[j][2]=0.f; rs[j][3]=0.f; }
  float asum = 0.f;

  float4 sv[5]; float se[5];

  auto issue_loads = [&](int ck) {
    const float* g0 = f2b + (size_t)(cc0 + ck*8)*CHW;
#pragma unroll
    for (int j = 0; j < 5; ++j) if (valid[j]) {
      const float* g = g0 + goff[j];
      sv[j] = *(const float4*)g;
      se[j] = g[qlt5[j] ? 4 : 0];       // always in-bounds
    }
  };
  auto pack_write = [&](int bufbase) {
#pragma unroll
    for (int j = 0; j < 5; ++j) if (valid[j]) {
      float4 v = sv[j];
      float e4 = qlt5[j] ? se[j] : 0.f;
      uint2 c0; c0.x = pk2(v.x, v.y); c0.y = pk2(v.z, v.w);
      uint2 c1; c1.x = pk2(v.y, v.z); c1.y = pk2(v.w, e4);
      *(uint2*)&smu[bufbase + wo0[j]]       = c0;   // copy0: elems (4q..4q+3)
      *(uint2*)&smu[bufbase + wo0[j] + RDW] = c1;   // copy1: elems (4q+1..4q+4)
      rs[j][0] = fmaf(v.x, v.x, rs[j][0]);
      rs[j][1] = fmaf(v.y, v.y, rs[j][1]);
      rs[j][2] = fmaf(v.z, v.z, rs[j][2]);
      rs[j][3] = fmaf(v.w, v.w, rs[j][3]);
    }
  };
  auto compute = [&](int ck, int bufbase) {
    const int chb = cc0 + ck*8;
#pragma unroll
    for (int ks = 0; ks < 4; ++ks) {
      const float* ap = f1b + (size_t)(chb + ks*2 + coff)*CHW + aoff;
      float4 a0 = *(const float4*)ap;
      float4 a1 = *(const float4*)(ap + 4);
      if (wid == 0) {
        asum = fmaf(a0.x,a0.x, fmaf(a0.y,a0.y, fmaf(a0.z,a0.z, fmaf(a0.w,a0.w, asum))));
        asum = fmaf(a1.x,a1.x, fmaf(a1.y,a1.y, fmaf(a1.z,a1.z, fmaf(a1.w,a1.w, asum))));
      }
      union { unsigned u[4]; bf16x8 v; } A_;
      A_.u[0] = pk2(a0.x, a0.y); A_.u[1] = pk2(a0.z, a0.w);
      A_.u[2] = pk2(a1.x, a1.y); A_.u[3] = pk2(a1.z, a1.w);
      const unsigned* cbp = smu + bufbase + (ks*2 + coff)*CSTR;
#pragma unroll
      for (int j = 0; j < 3; ++j) {
        if (j < tcnt) {                 // wave-uniform
          const unsigned* bp = cbp + boffb[j];
          union { unsigned u[4]; bf16x8 v; } B_;
          B_.u[0] = bp[0]; B_.u[1] = bp[1]; B_.u[2] = bp[2]; B_.u[3] = bp[3];
          acc[j] = __builtin_amdgcn_mfma_f32_16x16x32_bf16(A_.v, B_.v, acc[j], 0, 0, 0);
        }
      }
    }
  };

  // ---- prologue
  issue_loads(0);
  pack_write(0);
  if (NCHUNK > 1) issue_loads(1);
  __syncthreads();

  // ---- pipelined main loop: one barrier per chunk
  for (int ck = 0; ck < NCHUNK; ++ck) {
    const int cur = (ck & 1) * BUFDW;
    const int nxt = ((ck + 1) & 1) * BUFDW;
    if (ck + 1 < NCHUNK) pack_write(nxt);      // writes buffer not being read
    if (ck + 2 < NCHUNK) issue_loads(ck + 2);  // HBM latency hides under compute
    compute(ck, cur);
    __syncthreads();
  }

  // ---- merge phase (overlay on dead region)
  // phase 1: zero RS/ASUM; write S direct (disjoint tiles, full coverage)
  for (int i = tid; i < (OVL_END - RS0); i += 256) smf[RS0 + i] = 0.f;
#pragma unroll
  for (int j = 0; j < 3; ++j) {
    if (j < tcnt) {
      int v = tstart + j;
#pragma unroll
      for (int r = 0; r < 4; ++r)
        smf[S0 + (kb*4 + r)*LN + v*16 + row16] = acc[j][r];
    }
  }
  __syncthreads();

  // phase 2: RS atomics + asum
#pragma unroll
  for (int j = 0; j < 5; ++j) if (valid[j]) {
#pragma unroll
    for (int k = 0; k < 4; ++k)
      atomicAdd(&smf[RS0 + rpos[j] + k], rs[j][k]);
  }
  if (wid == 0) {
    float vs = asum;
#pragma unroll
    for (int off = 32; off; off >>= 1) vs += __shfl_xor(vs, off);
    if (lane == 0) smf[ASUM0] = vs;
  }
  __syncthreads();

  // phase 3: CS sliding 16-window sums
  if (tid < 154) {
    int yw = tid / 7, o = tid - 7*yw;
    float s = 0.f;
#pragma unroll
    for (int x = 0; x < 16; ++x) s += smf[RS0 + yw*RW + OX + o + x];
    smf[CS0 + tid] = s;
  }
  __syncthreads();

  // phase 4: distances
  if constexpr (NZ == 2) {
    if (tid < NSH) {
      int t = tid / 7, u = tid - 7*t;
      int oyt = iclamp(t + ey, 0, 6);
      int o   = iclamp(u + ex, 0, 6);
      float s = smf[ASUM0];
#pragma unroll
      for (int y = 0; y < 16; ++y) {
        int n = (y + oyt)*7 + o;
        s += smf[CS0 + n] - 2.f*smf[S0 + y*LN + n];
      }
      partial[((size_t)(b*NBLK + blk)*2 + z)*NSH + tid] = s;   // raw z-partial
    }
  } else {
    if (tid < 64) {
      int tu = tid < NSH ? tid : NSH-1;
      int t = tu / 7, u = tu - 7*t;
      int oyt = iclamp(t + ey, 0, 6);
      int o   = iclamp(u + ex, 0, 6);
      float s = smf[ASUM0];
#pragma unroll
      for (int y = 0; y < 16; ++y) {
        int n = (y + oyt)*7 + o;
        s += smf[CS0 + n] - 2.f*smf[S0 + y*LN + n];
      }
#pragma unroll
      for (int off = 32; off; off >>= 1) s = fminf(s, __shfl_xor(s, off));
      if (tid == 0) partial[(size_t)b*NBLK + blk] = s;
    }
  }
}

template<int NZ>
__global__ void topk_kernel(const float* __restrict__ partial, float* __restrict__ out)
{
  const int b = blockIdx.x;
  const int lane = threadIdx.x;
  const float INF = __builtin_inff();

  float v0 = INF, v1 = INF, v2 = INF;
  if constexpr (NZ == 2) {
#pragma unroll
    for (int i = 0; i < 3; i++) {
      int blk = lane + 64*i;
      if (blk < NBLK) {
        const float* p = partial + (size_t)(b*NBLK + blk)*2*NSH;
        float m = INF;
        for (int k = 0; k < NSH; k++) m = fminf(m, p[k] + p[k+NSH]);
        if (i == 0) v0 = m; else if (i == 1) v1 = m; else v2 = m;
      }
    }
  } else {
    const float* p = partial + (size_t)b*NBLK;
    v0 = p[lane];
    v1 = p[lane + 64];
    v2 = (lane < 16) ? p[lane + 128] : INF;
  }

  float sum = 0.f;
  for (int it = 0; it < 16; ++it) {
    float lm = fminf(v0, fminf(v1, v2));
    float m = lm;
#pragma unroll
    for (int off = 32; off; off >>= 1) m = fminf(m, __shfl_xor(m, off));
    sum += m;
    unsigned long long mask = __ballot(lm == m);
    int leader = __ffsll(mask) - 1;
    if (lane == leader) {
      if (v0 == m)      v0 = INF;
      else if (v1 == m) v1 = INF;
      else              v2 = INF;
    }
  }
  if (lane == 0) out[b] = sum * (1.0f/((float)CC*SS*SS));
}

extern "C" void kernel_launch(void* const* d_in, const int* in_sizes, int n_in,
                              void* d_out, int out_size, void* d_ws, size_t ws_size,
                              hipStream_t stream)
{
  const float* fm1 = (const float*)d_in[0];
  const float* fm2 = (const float*)d_in[1];
  float* out  = (float*)d_out;
  float* scratch = (float*)d_ws;

  const size_t NEED = (size_t)8 * NBLK * 2 * NSH * sizeof(float);  // 451,584 B
  if (ws_size >= NEED) {
    dist_kernel<2><<<2*8*NBLK, 256, 0, stream>>>(fm1, fm2, scratch);
    topk_kernel<2><<<8, 64, 0, stream>>>(scratch, out);
  } else {
    dist_kernel<1><<<8*NBLK, 256, 0, stream>>>(fm1, fm2, scratch);
    topk_kernel<1><<<8, 64, 0, stream>>>(scratch, out);
  }
}

// Round 11
// 112.028 us; speedup vs baseline: 1.9207x; 1.1380x over previous
//
#include <hip/hip_runtime.h>
#include <math.h>

#define HH 192
#define WW 192
#define CC 64
#define CHW (HH*WW)
#define SS 16
#define NB 12
#define NBLK 144
#define CCH 8            // channels per LDS chunk
#define UROW 22          // union region rows
#define LROW 28          // padded LDS row stride (floats); 24 data + 4 pad (swizzle room)
#define QN 6             // float4 staged per row (24 floats)
#define NSH 49
#define STAGE_N (CCH*UROW*QN)   // 1056 float4 per chunk
// overlay (dwords, after region is dead)
#define CORR0 0
#define WACC0 (CORR0 + NSH)     // 49..202
#define ASUM0 (WACC0 + UROW*7)  // 203

__device__ __forceinline__ int iclamp(int v, int lo, int hi){ return v<lo?lo:(v>hi?hi:v); }
__device__ __forceinline__ int rowoff(int r){ return ((r>>3)&1)*4; }   // bank de-alias

// EX: column-shift class (-3 left, 0 interior, +3 right); OX: compile-time col offset
template<int EX, int OX, int NCH>
__device__ __forceinline__ void run_chunks(
    const float* __restrict__ f1b, const float* __restrict__ f2b,
    float* sm, int tid, int t, int y, int h8,
    int ys, int xs, int rbase, int ey, int cc0,
    float acc[7], float wacc[7], float& asum)
{
  const int cbase4 = (EX == -3) ? 0 : ((EX == 0) ? (xs - 4) : (WW - LROW + 4));
  const int oyt = iclamp(t + ey, 0, 6);
  const float* ap0 = f1b + (size_t)(ys + y)*WW + xs + h8;
  const int wrow = (y + oyt)*LROW + rowoff(y + oyt) + h8;
  const bool isCorr = (t < 7);
  const int r = tid - 224;              // wrow lane's row (valid when t==7)
  const bool isWrow = (t == 7) && (r < UROW);

  for (int ch0 = 0; ch0 < NCH; ch0 += CCH) {
    const int cc = cc0 + ch0;
    // ---- stage fm2 union region [cc..cc+7][rbase..+21][cbase4..+23]
    for (int i = tid; i < STAGE_N; i += 256) {
      int ch  = i / (UROW*QN);
      int rem = i - ch*(UROW*QN);
      int rr  = rem / QN;
      int q   = rem - rr*QN;
      *(float4*)&sm[ch*(UROW*LROW) + rr*LROW + rowoff(rr) + 4*q] =
        *(const float4*)(f2b + (size_t)(cc+ch)*CHW + (size_t)(rbase+rr)*WW + cbase4 + 4*q);
    }
    __syncthreads();

    if (isCorr) {
#pragma unroll 2
      for (int c = 0; c < CCH; c++) {
        const float* ap = ap0 + (size_t)(cc + c)*CHW;   // fm1 half-row (L1-reused x7)
        float a[8];
        {
          float4 v0 = *(const float4*)(ap + 0);
          float4 v1 = *(const float4*)(ap + 4);
          a[0]=v0.x; a[1]=v0.y; a[2]=v0.z; a[3]=v0.w;
          a[4]=v1.x; a[5]=v1.y; a[6]=v1.z; a[7]=v1.w;
        }
        if (t == 0) {                                   // block a^2 (once, not per shift)
          asum = fmaf(a[0],a[0], fmaf(a[1],a[1], fmaf(a[2],a[2], fmaf(a[3],a[3], asum))));
          asum = fmaf(a[4],a[4], fmaf(a[5],a[5], fmaf(a[6],a[6], fmaf(a[7],a[7], asum))));
        }
        const float* wp = sm + c*(UROW*LROW) + wrow;
        float w[16];
#pragma unroll
        for (int j = 0; j < 4; j++) {
          float4 v = *(const float4*)(wp + 4*j);        // aligned ds_read_b128
          w[4*j]=v.x; w[4*j+1]=v.y; w[4*j+2]=v.z; w[4*j+3]=v.w;
        }
#pragma unroll
        for (int u = 0; u < 7; u++) {
          const int o = ((u+EX) < 0 ? 0 : ((u+EX) > 6 ? 6 : (u+EX))) + OX;  // compile-time
          float s0 = 0.f, s1 = 0.f;
#pragma unroll
          for (int x = 0; x < 8; x += 2) {
            s0 = fmaf(a[x],   w[o+x],   s0);            // 1 FMA per MAC (corr)
            s1 = fmaf(a[x+1], w[o+x+1], s1);
          }
          acc[u] += s0 + s1;
        }
      }
    } else if (isWrow) {
      // ---- w^2 sliding-window row sums: lane owns region row r, all 7 offsets
      const int rbOff = r*LROW + rowoff(r);
#pragma unroll 1
      for (int c = 0; c < CCH; c++) {
        const float* wp = sm + c*(UROW*LROW) + rbOff;
        float w[24];
#pragma unroll
        for (int j = 0; j < 6; j++) {
          float4 v = *(const float4*)(wp + 4*j);
          w[4*j]=v.x; w[4*j+1]=v.y; w[4*j+2]=v.z; w[4*j+3]=v.w;
        }
        float W = 0.f;
#pragma unroll
        for (int x = 0; x < 16; x++) W = fmaf(w[OX+x], w[OX+x], W);
        wacc[0] += W;
#pragma unroll
        for (int oo = 1; oo < 7; oo++) {
          W += w[OX+oo+15]*w[OX+oo+15] - w[OX+oo-1]*w[OX+oo-1];
          wacc[oo] += W;
        }
      }
    }
    __syncthreads();
  }
}

// NZ: channel split; 1D grid, XCD-pinned raster swizzle (b = wg&7 fixed per XCD)
template<int NZ>
__global__ __launch_bounds__(256, 8) void dist_kernel(
    const float* __restrict__ fm1, const float* __restrict__ fm2,
    float* __restrict__ partial)
{
  __shared__ float sm[CCH*UROW*LROW];   // 19,712 B; CORR/WACC/ASUM overlaid after compute

  const int wg  = blockIdx.x;           // [0, NZ*1152)
  const int z   = (NZ == 2 && wg >= 8*NBLK) ? 1 : 0;
  const int w2  = wg - z*8*NBLK;
  const int b   = w2 & 7;               // batch pinned per XCD
  const int blk = w2 >> 3;              // raster (halo L2 reuse)
  const int by  = blk / NB, bx = blk - by*NB;
  const int ys  = by*SS, xs = bx*SS;
  const int rbase = iclamp(ys-3, 0, HH-UROW);
  const int ey = (ys-3) - rbase;        // in {-3,0,3}
  const int cbase = iclamp(xs-3, 0, WW-UROW);
  const int ex = (xs-3) - cbase;        // -3/0/3

  const int tid = threadIdx.x;
  const int t   = tid >> 5;             // 0..7 ; t<7 corr (dh=t-3), t==7 wrow
  const int y   = (tid & 31) >> 1;      // 0..15
  const int h8  = (tid & 1) * 8;

  const float* f1b = fm1 + (size_t)b*CC*CHW;
  const float* f2b = fm2 + (size_t)b*CC*CHW;
  const int cc0 = z * (CC/NZ);

  float acc[7], wacc[7];
#pragma unroll
  for (int k = 0; k < 7; k++) { acc[k] = 0.f; wacc[k] = 0.f; }
  float asum = 0.f;

  if (bx == 0)
    run_chunks<-3,0,CC/NZ>(f1b, f2b, sm, tid, t, y, h8, ys, xs, rbase, ey, cc0, acc, wacc, asum);
  else if (bx == NB-1)
    run_chunks< 3,2,CC/NZ>(f1b, f2b, sm, tid, t, y, h8, ys, xs, rbase, ey, cc0, acc, wacc, asum);
  else
    run_chunks< 0,1,CC/NZ>(f1b, f2b, sm, tid, t, y, h8, ys, xs, rbase, ey, cc0, acc, wacc, asum);

  // ---- overlay merge (region dead after final barrier of run_chunks)
  // corr: reduce over 32-lane (y,h8) group
#pragma unroll
  for (int u = 0; u < 7; u++) {
    float v = acc[u];
#pragma unroll
    for (int off = 16; off; off >>= 1) v += __shfl_xor(v, off);
    if (t < 7 && (tid & 31) == 0) sm[CORR0 + t*7 + u] = v;
  }
  // wrow lanes dump register accumulators
  {
    const int r = tid - 224;
    if (t == 7 && r < UROW) {
#pragma unroll
      for (int oo = 0; oo < 7; oo++) sm[WACC0 + r*7 + oo] = wacc[oo];
    }
  }
  // asum: t==0 group holds full block sum
  {
    float v = asum;
#pragma unroll
    for (int off = 16; off; off >>= 1) v += __shfl_xor(v, off);
    if (tid == 0) sm[ASUM0] = v;
  }
  __syncthreads();

  if constexpr (NZ == 2) {
    if (tid < NSH) {
      int tt = tid / 7, u = tid - 7*tt;
      int oyt = iclamp(tt + ey, 0, 6);
      int oi  = iclamp(u + ex, 0, 6);
      float s = sm[ASUM0] - 2.f*sm[CORR0 + tid];
#pragma unroll
      for (int yy = 0; yy < 16; ++yy) s += sm[WACC0 + (yy + oyt)*7 + oi];
      partial[((size_t)(b*NBLK + blk)*2 + z)*NSH + tid] = s;   // raw z-partial
    }
  } else {
    if (tid < 64) {
      int tu = tid < NSH ? tid : NSH-1;
      int tt = tu / 7, u = tu - 7*tt;
      int oyt = iclamp(tt + ey, 0, 6);
      int oi  = iclamp(u + ex, 0, 6);
      float s = sm[ASUM0] - 2.f*sm[CORR0 + tu];
#pragma unroll
      for (int yy = 0; yy < 16; ++yy) s += sm[WACC0 + (yy + oyt)*7 + oi];
#pragma unroll
      for (int off = 32; off; off >>= 1) s = fminf(s, __shfl_xor(s, off));
      if (tid == 0) partial[(size_t)b*NBLK + blk] = s;         // raw min
    }
  }
}

template<int NZ>
__global__ void topk_kernel(const float* __restrict__ partial, float* __restrict__ out)
{
  const int b = blockIdx.x;
  const int lane = threadIdx.x;
  const float INF = __builtin_inff();

  float v0 = INF, v1 = INF, v2 = INF;
  if constexpr (NZ == 2) {
#pragma unroll
    for (int i = 0; i < 3; i++) {
      int blk = lane + 64*i;
      if (blk < NBLK) {
        const float* p = partial + (size_t)(b*NBLK + blk)*2*NSH;
        float m = INF;
        for (int k = 0; k < NSH; k++) m = fminf(m, p[k] + p[k+NSH]);
        if (i == 0) v0 = m; else if (i == 1) v1 = m; else v2 = m;
      }
    }
  } else {
    const float* p = partial + (size_t)b*NBLK;
    v0 = p[lane];
    v1 = p[lane + 64];
    v2 = (lane < 16) ? p[lane + 128] : INF;
  }

  float sum = 0.f;
  for (int it = 0; it < 16; ++it) {
    float lm = fminf(v0, fminf(v1, v2));
    float m = lm;
#pragma unroll
    for (int off = 32; off; off >>= 1) m = fminf(m, __shfl_xor(m, off));
    sum += m;
    unsigned long long mask = __ballot(lm == m);
    int leader = __ffsll(mask) - 1;
    if (lane == leader) {
      if (v0 == m)      v0 = INF;
      else if (v1 == m) v1 = INF;
      else              v2 = INF;
    }
  }
  if (lane == 0) out[b] = sum * (1.0f/((float)CC*SS*SS));
}

extern "C" void kernel_launch(void* const* d_in, const int* in_sizes, int n_in,
                              void* d_out, int out_size, void* d_ws, size_t ws_size,
                              hipStream_t stream)
{
  const float* fm1 = (const float*)d_in[0];
  const float* fm2 = (const float*)d_in[1];
  float* out  = (float*)d_out;
  float* scratch = (float*)d_ws;

  const size_t NEED = (size_t)8 * NBLK * 2 * NSH * sizeof(float);  // 451,584 B
  if (ws_size >= NEED) {
    dist_kernel<2><<<2*8*NBLK, 256, 0, stream>>>(fm1, fm2, scratch);
    topk_kernel<2><<<8, 64, 0, stream>>>(scratch, out);
  } else {
    dist_kernel<1><<<8*NBLK, 256, 0, stream>>>(fm1, fm2, scratch);
    topk_kernel<1><<<8, 64, 0, stream>>>(scratch, out);
  }
}

// Round 12
// 109.249 us; speedup vs baseline: 1.9695x; 1.0254x over previous
//
#include <hip/hip_runtime.h>
#include <math.h>

#define HH 192
#define WW 192
#define CC 64
#define CHW (HH*WW)
#define SS 16
#define NB 12
#define NBLK 144
#define CCH 8            // channels per LDS chunk
#define UROW 22          // union region rows
#define LROW 28          // padded LDS row stride (floats)
#define QN 6             // float4 staged per row (24 floats)
#define NSH 49
#define STAGE_N (CCH*UROW*QN)   // 1056 float4 per chunk
// overlay (dwords, after region is dead)
#define PART0 0
#define ASUM0 NSH               // 49

__device__ __forceinline__ int iclamp(int v, int lo, int hi){ return v<lo?lo:(v>hi?hi:v); }

// EX: column-shift class (-3 left, 0 interior, +3 right); OX: compile-time col offset
template<int EX, int OX, int NCH>
__device__ __forceinline__ void run_chunks(
    const float* __restrict__ f1b, const float* __restrict__ f2b,
    float* sm, int tid, int t, int y, int h8, bool active,
    int ys, int xs, int rbase, int ey, int cc0,
    float acc[7], float& asum)
{
  const int cbase4 = (EX == -3) ? 0 : ((EX == 0) ? (xs - 4) : (WW - LROW + 4));
  const int oyt = iclamp(t + ey, 0, 6);
  const float* ap0 = f1b + (size_t)(ys + y)*WW + xs + h8;
  const int wrow = (y + oyt)*LROW + h8;

  constexpr int OMIN = ((0+EX) < 0 ? 0 : ((0+EX) > 6 ? 6 : (0+EX))) + OX;
  constexpr int OMAX = ((6+EX) < 0 ? 0 : ((6+EX) > 6 ? 6 : (6+EX))) + OX;
  constexpr int NW = OMAX - OMIN + 1;      // <=7 ; OMAX+7 <= 15 fits w[16]

  for (int ch0 = 0; ch0 < NCH; ch0 += CCH) {
    const int cc = cc0 + ch0;
    // ---- stage fm2 union region [cc..cc+7][rbase..+21][cbase4..+23]
    for (int i = tid; i < STAGE_N; i += 256) {
      int ch  = i / (UROW*QN);
      int rem = i - ch*(UROW*QN);
      int r   = rem / QN;
      int q   = rem - r*QN;
      *(float4*)&sm[ch*(UROW*LROW) + r*LROW + 4*q] =
        *(const float4*)(f2b + (size_t)(cc+ch)*CHW + (size_t)(rbase+r)*WW + cbase4 + 4*q);
    }
    __syncthreads();

    if (active) {
#pragma unroll 2
      for (int c = 0; c < CCH; c++) {
        const float* ap = ap0 + (size_t)(cc + c)*CHW;   // fm1 half-row (L1-reused x7)
        float a[8];
        {
          float4 v0 = *(const float4*)(ap + 0);
          float4 v1 = *(const float4*)(ap + 4);
          a[0]=v0.x; a[1]=v0.y; a[2]=v0.z; a[3]=v0.w;
          a[4]=v1.x; a[5]=v1.y; a[6]=v1.z; a[7]=v1.w;
        }
        if (t == 0) {                                   // block a^2 once per (y,h8,c)
          asum = fmaf(a[0],a[0], fmaf(a[1],a[1], fmaf(a[2],a[2], fmaf(a[3],a[3], asum))));
          asum = fmaf(a[4],a[4], fmaf(a[5],a[5], fmaf(a[6],a[6], fmaf(a[7],a[7], asum))));
        }
        const float* wp = sm + c*(UROW*LROW) + wrow;
        float w[16];
#pragma unroll
        for (int j = 0; j < 4; j++) {
          float4 v = *(const float4*)(wp + 4*j);        // conflict-free ds_read_b128
          w[4*j]=v.x; w[4*j+1]=v.y; w[4*j+2]=v.z; w[4*j+3]=v.w;
        }
        // sliding 8-wide w^2 windows, compile-time offsets
        float W[NW];
        {
          float s = 0.f;
#pragma unroll
          for (int x = 0; x < 8; x++) s = fmaf(w[OMIN+x], w[OMIN+x], s);
          W[0] = s;
#pragma unroll
          for (int j = 1; j < NW; j++) {
            s = fmaf(w[OMIN+j+7], w[OMIN+j+7], s);
            s = fmaf(-w[OMIN+j-1], w[OMIN+j-1], s);
            W[j] = s;
          }
        }
#pragma unroll
        for (int u = 0; u < 7; u++) {
          const int o = ((u+EX) < 0 ? 0 : ((u+EX) > 6 ? 6 : (u+EX))) + OX;  // folds
          float s0 = 0.f, s1 = 0.f;
#pragma unroll
          for (int x = 0; x < 8; x += 2) {
            s0 = fmaf(a[x],   w[o+x],   s0);            // 1 FMA per MAC
            s1 = fmaf(a[x+1], w[o+x+1], s1);
          }
          acc[u] = fmaf(-2.f, s0 + s1, acc[u] + W[o-OMIN]);
        }
      }
    }
    __syncthreads();
  }
}

// NZ: channel split; 1D grid, XCD-pinned raster swizzle (b = wg&7 fixed per XCD)
template<int NZ>
__global__ __launch_bounds__(256, 8) void dist_kernel(
    const float* __restrict__ fm1, const float* __restrict__ fm2,
    float* __restrict__ partial)
{
  __shared__ float sm[CCH*UROW*LROW];   // 19,712 B; PART/ASUM overlaid after compute

  const int wg  = blockIdx.x;           // [0, NZ*1152)
  const int z   = (NZ == 2 && wg >= 8*NBLK) ? 1 : 0;
  const int w2  = wg - z*8*NBLK;
  const int b   = w2 & 7;               // batch pinned per XCD
  const int blk = w2 >> 3;              // raster (halo L2 reuse)
  const int by  = blk / NB, bx = blk - by*NB;
  const int ys  = by*SS, xs = bx*SS;
  const int rbase = iclamp(ys-3, 0, HH-UROW);
  const int ey = (ys-3) - rbase;        // in {-3,0,3}
  const int cbase = iclamp(xs-3, 0, WW-UROW);
  const int ex = (xs-3) - cbase;        // -3/0/3

  const int tid = threadIdx.x;
  const int t   = tid >> 5;             // 0..7 ; t<7 active (dh = t-3)
  const int y   = tid & 15;             // consecutive lanes = consecutive rows
  const int h8  = ((tid >> 4) & 1) * 8; // x-half: cols [h8, h8+8)
  const bool active = (t < 7);

  const float* f1b = fm1 + (size_t)b*CC*CHW;
  const float* f2b = fm2 + (size_t)b*CC*CHW;
  const int cc0 = z * (CC/NZ);

  float acc[7];
#pragma unroll
  for (int k = 0; k < 7; k++) acc[k] = 0.f;
  float asum = 0.f;

  if (bx == 0)
    run_chunks<-3,0,CC/NZ>(f1b, f2b, sm, tid, t, y, h8, active, ys, xs, rbase, ey, cc0, acc, asum);
  else if (bx == NB-1)
    run_chunks< 3,2,CC/NZ>(f1b, f2b, sm, tid, t, y, h8, active, ys, xs, rbase, ey, cc0, acc, asum);
  else
    run_chunks< 0,1,CC/NZ>(f1b, f2b, sm, tid, t, y, h8, active, ys, xs, rbase, ey, cc0, acc, asum);

  // ---- overlay merge (region dead after final barrier of run_chunks)
  float* distk = sm;                    // PART[49] at 0, ASUM at 49
#pragma unroll
  for (int u = 0; u < 7; u++) {
    float v = acc[u];
#pragma unroll
    for (int off = 16; off; off >>= 1) v += __shfl_xor(v, off);
    if (active && (tid & 31) == 0) distk[PART0 + t*7 + u] = v;
  }
  {
    float v = asum;                     // t==0 group holds full block a^2
#pragma unroll
    for (int off = 16; off; off >>= 1) v += __shfl_xor(v, off);
    if (tid == 0) distk[ASUM0] = v;
  }
  __syncthreads();

  if constexpr (NZ == 2) {
    if (tid < NSH)
      partial[((size_t)(b*NBLK + blk)*2 + z)*NSH + tid] =
        distk[ASUM0] + distk[PART0 + tid];               // raw z-partial
  } else {
    if (tid < 64) {
      float s = (tid < NSH) ? (distk[ASUM0] + distk[PART0 + tid]) : __builtin_inff();
#pragma unroll
      for (int off = 32; off; off >>= 1) s = fminf(s, __shfl_xor(s, off));
      if (tid == 0) partial[(size_t)b*NBLK + blk] = s;   // raw min
    }
  }
}

template<int NZ>
__global__ void topk_kernel(const float* __restrict__ partial, float* __restrict__ out)
{
  const int b = blockIdx.x;
  const int lane = threadIdx.x;
  const float INF = __builtin_inff();

  float v0 = INF, v1 = INF, v2 = INF;
  if constexpr (NZ == 2) {
#pragma unroll
    for (int i = 0; i < 3; i++) {
      int blk = lane + 64*i;
      if (blk < NBLK) {
        const float* p = partial + (size_t)(b*NBLK + blk)*2*NSH;
        float m = INF;
        for (int k = 0; k < NSH; k++) m = fminf(m, p[k] + p[k+NSH]);
        if (i == 0) v0 = m; else if (i == 1) v1 = m; else v2 = m;
      }
    }
  } else {
    const float* p = partial + (size_t)b*NBLK;
    v0 = p[lane];
    v1 = p[lane + 64];
    v2 = (lane < 16) ? p[lane + 128] : INF;
  }

  float sum = 0.f;
  for (int it = 0; it < 16; ++it) {
    float lm = fminf(v0, fminf(v1, v2));
    float m = lm;
#pragma unroll
    for (int off = 32; off; off >>= 1) m = fminf(m, __shfl_xor(m, off));
    sum += m;
    unsigned long long mask = __ballot(lm == m);
    int leader = __ffsll(mask) - 1;
    if (lane == leader) {
      if (v0 == m)      v0 = INF;
      else if (v1 == m) v1 = INF;
      else              v2 = INF;
    }
  }
  if (lane == 0) out[b] = sum * (1.0f/((float)CC*SS*SS));
}

extern "C" void kernel_launch(void* const* d_in, const int* in_sizes, int n_in,
                              void* d_out, int out_size, void* d_ws, size_t ws_size,
                              hipStream_t stream)
{
  const float* fm1 = (const float*)d_in[0];
  const float* fm2 = (const float*)d_in[1];
  float* out  = (float*)d_out;
  float* scratch = (float*)d_ws;

  const size_t NEED = (size_t)8 * NBLK * 2 * NSH * sizeof(float);  // 451,584 B
  if (ws_size >= NEED) {
    dist_kernel<2><<<2*8*NBLK, 256, 0, stream>>>(fm1, fm2, scratch);
    topk_kernel<2><<<8, 64, 0, stream>>>(scratch, out);
  } else {
    dist_kernel<1><<<8*NBLK, 256, 0, stream>>>(fm1, fm2, scratch);
    topk_kernel<1><<<8, 64, 0, stream>>>(scratch, out);
  }
}

// Round 13
// 109.178 us; speedup vs baseline: 1.9708x; 1.0007x over previous
//
#include <hip/hip_runtime.h>
#include <math.h>

#define HH 192
#define WW 192
#define CC 64
#define CHW (HH*WW)
#define SS 16
#define NB 12
#define NBLK 144
#define CCH 8            // channels per LDS chunk
#define UROW 22          // union region rows
#define LROW 28          // padded LDS row stride (floats)
#define QN 6             // float4 staged per row (24 floats)
#define NSH 49
#define STAGE_N (CCH*UROW*QN)   // 1056 float4 per chunk
// overlay (dwords, after region is dead)
#define PART0 0
#define ASUM0 NSH               // 49

__device__ __forceinline__ int iclamp(int v, int lo, int hi){ return v<lo?lo:(v>hi?hi:v); }

// EX: column-shift class (-3 left, 0 interior, +3 right); OX: compile-time col offset
template<int EX, int OX, int NCH>
__device__ __forceinline__ void run_chunks(
    const float* __restrict__ f1b, const float* __restrict__ f2b,
    float* sm, int tid, int t, int y, int h8, bool active,
    int ys, int xs, int rbase, int ey, int cc0,
    float acc[7], float& asum)
{
  const int cbase4 = (EX == -3) ? 0 : ((EX == 0) ? (xs - 4) : (WW - LROW + 4));
  const int oyt = iclamp(t + ey, 0, 6);
  const float* ap0 = f1b + (size_t)(ys + y)*WW + xs + h8;
  const int wrow = (y + oyt)*LROW + h8;

  constexpr int OMIN = ((0+EX) < 0 ? 0 : ((0+EX) > 6 ? 6 : (0+EX))) + OX;
  constexpr int OMAX = ((6+EX) < 0 ? 0 : ((6+EX) > 6 ? 6 : (6+EX))) + OX;
  constexpr int NW = OMAX - OMIN + 1;      // <=7 ; OMAX+7 <= 15 fits w[16]

  for (int ch0 = 0; ch0 < NCH; ch0 += CCH) {
    const int cc = cc0 + ch0;
    // ---- stage fm2 union region [cc..cc+7][rbase..+21][cbase4..+23]
    for (int i = tid; i < STAGE_N; i += 256) {
      int ch  = i / (UROW*QN);
      int rem = i - ch*(UROW*QN);
      int r   = rem / QN;
      int q   = rem - r*QN;
      *(float4*)&sm[ch*(UROW*LROW) + r*LROW + 4*q] =
        *(const float4*)(f2b + (size_t)(cc+ch)*CHW + (size_t)(rbase+r)*WW + cbase4 + 4*q);
    }
    __syncthreads();

    if (active) {
#pragma unroll 2
      for (int c = 0; c < CCH; c++) {
        const float* ap = ap0 + (size_t)(cc + c)*CHW;   // fm1 half-row (L1-reused x7)
        float a[8];
        {
          float4 v0 = *(const float4*)(ap + 0);
          float4 v1 = *(const float4*)(ap + 4);
          a[0]=v0.x; a[1]=v0.y; a[2]=v0.z; a[3]=v0.w;
          a[4]=v1.x; a[5]=v1.y; a[6]=v1.z; a[7]=v1.w;
        }
        if (t == 0) {                                   // block a^2 once per (y,h8,c)
          asum = fmaf(a[0],a[0], fmaf(a[1],a[1], fmaf(a[2],a[2], fmaf(a[3],a[3], asum))));
          asum = fmaf(a[4],a[4], fmaf(a[5],a[5], fmaf(a[6],a[6], fmaf(a[7],a[7], asum))));
        }
        const float* wp = sm + c*(UROW*LROW) + wrow;
        float w[16];
#pragma unroll
        for (int j = 0; j < 4; j++) {
          float4 v = *(const float4*)(wp + 4*j);        // ds_read_b128, conflict-free map
          w[4*j]=v.x; w[4*j+1]=v.y; w[4*j+2]=v.z; w[4*j+3]=v.w;
        }
        // sliding 8-wide w^2 windows, compile-time offsets
        float W[NW];
        {
          float s = 0.f;
#pragma unroll
          for (int x = 0; x < 8; x++) s = fmaf(w[OMIN+x], w[OMIN+x], s);
          W[0] = s;
#pragma unroll
          for (int j = 1; j < NW; j++) {
            s = fmaf(w[OMIN+j+7], w[OMIN+j+7], s);
            s = fmaf(-w[OMIN+j-1], w[OMIN+j-1], s);
            W[j] = s;
          }
        }
#pragma unroll
        for (int u = 0; u < 7; u++) {
          const int o = ((u+EX) < 0 ? 0 : ((u+EX) > 6 ? 6 : (u+EX))) + OX;  // folds
          float s0 = 0.f, s1 = 0.f;
#pragma unroll
          for (int x = 0; x < 8; x += 2) {
            s0 = fmaf(a[x],   w[o+x],   s0);            // 1 FMA per MAC
            s1 = fmaf(a[x+1], w[o+x+1], s1);
          }
          acc[u] = fmaf(-2.f, s0 + s1, acc[u] + W[o-OMIN]);
        }
      }
    }
    __syncthreads();
  }
}

// NZ: channel split; 1D grid, XCD-pinned raster swizzle (b = wg&7 fixed per XCD)
template<int NZ>
__global__ __launch_bounds__(256, 4) void dist_kernel(
    const float* __restrict__ fm1, const float* __restrict__ fm2,
    float* __restrict__ partial)
{
  __shared__ float sm[CCH*UROW*LROW];   // 19,712 B; PART/ASUM overlaid after compute

  const int wg  = blockIdx.x;           // [0, NZ*1152)
  const int z   = (NZ == 2 && wg >= 8*NBLK) ? 1 : 0;
  const int w2  = wg - z*8*NBLK;
  const int b   = w2 & 7;               // batch pinned per XCD
  const int blk = w2 >> 3;              // raster (halo L2 reuse)
  const int by  = blk / NB, bx = blk - by*NB;
  const int ys  = by*SS, xs = bx*SS;
  const int rbase = iclamp(ys-3, 0, HH-UROW);
  const int ey = (ys-3) - rbase;        // in {-3,0,3}
  const int cbase = iclamp(xs-3, 0, WW-UROW);
  const int ex = (xs-3) - cbase;        // -3/0/3

  const int tid = threadIdx.x;
  const int t   = tid >> 5;             // 0..7 ; t<7 active (dh = t-3)
  const int y   = tid & 15;             // consecutive lanes = consecutive rows
  const int h8  = ((tid >> 4) & 1) * 8; // x-half: cols [h8, h8+8)
  const bool active = (t < 7);

  const float* f1b = fm1 + (size_t)b*CC*CHW;
  const float* f2b = fm2 + (size_t)b*CC*CHW;
  const int cc0 = z * (CC/NZ);

  float acc[7];
#pragma unroll
  for (int k = 0; k < 7; k++) acc[k] = 0.f;
  float asum = 0.f;

  if (bx == 0)
    run_chunks<-3,0,CC/NZ>(f1b, f2b, sm, tid, t, y, h8, active, ys, xs, rbase, ey, cc0, acc, asum);
  else if (bx == NB-1)
    run_chunks< 3,2,CC/NZ>(f1b, f2b, sm, tid, t, y, h8, active, ys, xs, rbase, ey, cc0, acc, asum);
  else
    run_chunks< 0,1,CC/NZ>(f1b, f2b, sm, tid, t, y, h8, active, ys, xs, rbase, ey, cc0, acc, asum);

  // ---- overlay merge (region dead after final barrier of run_chunks)
  float* distk = sm;                    // PART[49] at 0, ASUM at 49
#pragma unroll
  for (int u = 0; u < 7; u++) {
    float v = acc[u];
#pragma unroll
    for (int off = 16; off; off >>= 1) v += __shfl_xor(v, off);
    if (active && (tid & 31) == 0) distk[PART0 + t*7 + u] = v;
  }
  {
    float v = asum;                     // t==0 group holds full block a^2
#pragma unroll
    for (int off = 16; off; off >>= 1) v += __shfl_xor(v, off);
    if (tid == 0) distk[ASUM0] = v;
  }
  __syncthreads();

  if constexpr (NZ == 2) {
    if (tid < NSH)
      partial[((size_t)(b*NBLK + blk)*2 + z)*NSH + tid] =
        distk[ASUM0] + distk[PART0 + tid];               // raw z-partial
  } else {
    if (tid < 64) {
      float s = (tid < NSH) ? (distk[ASUM0] + distk[PART0 + tid]) : __builtin_inff();
#pragma unroll
      for (int off = 32; off; off >>= 1) s = fminf(s, __shfl_xor(s, off));
      if (tid == 0) partial[(size_t)b*NBLK + blk] = s;   // raw min
    }
  }
}

template<int NZ>
__global__ void topk_kernel(const float* __restrict__ partial, float* __restrict__ out)
{
  const int b = blockIdx.x;
  const int lane = threadIdx.x;
  const float INF = __builtin_inff();

  float v0 = INF, v1 = INF, v2 = INF;
  if constexpr (NZ == 2) {
#pragma unroll
    for (int i = 0; i < 3; i++) {
      int blk = lane + 64*i;
      if (blk < NBLK) {
        const float* p = partial + (size_t)(b*NBLK + blk)*2*NSH;
        float m = INF;
        for (int k = 0; k < NSH; k++) m = fminf(m, p[k] + p[k+NSH]);
        if (i == 0) v0 = m; else if (i == 1) v1 = m; else v2 = m;
      }
    }
  } else {
    const float* p = partial + (size_t)b*NBLK;
    v0 = p[lane];
    v1 = p[lane + 64];
    v2 = (lane < 16) ? p[lane + 128] : INF;
  }

  float sum = 0.f;
  for (int it = 0; it < 16; ++it) {
    float lm = fminf(v0, fminf(v1, v2));
    float m = lm;
#pragma unroll
    for (int off = 32; off; off >>= 1) m = fminf(m, __shfl_xor(m, off));
    sum += m;
    unsigned long long mask = __ballot(lm == m);
    int leader = __ffsll(mask) - 1;
    if (lane == leader) {
      if (v0 == m)      v0 = INF;
      else if (v1 == m) v1 = INF;
      else              v2 = INF;
    }
  }
  if (lane == 0) out[b] = sum * (1.0f/((float)CC*SS*SS));
}

extern "C" void kernel_launch(void* const* d_in, const int* in_sizes, int n_in,
                              void* d_out, int out_size, void* d_ws, size_t ws_size,
                              hipStream_t stream)
{
  const float* fm1 = (const float*)d_in[0];
  const float* fm2 = (const float*)d_in[1];
  float* out  = (float*)d_out;
  float* scratch = (float*)d_ws;

  const size_t NEED = (size_t)8 * NBLK * 2 * NSH * sizeof(float);  // 451,584 B
  if (ws_size >= NEED) {
    dist_kernel<2><<<2*8*NBLK, 256, 0, stream>>>(fm1, fm2, scratch);
    topk_kernel<2><<<8, 64, 0, stream>>>(scratch, out);
  } else {
    dist_kernel<1><<<8*NBLK, 256, 0, stream>>>(fm1, fm2, scratch);
    topk_kernel<1><<<8, 64, 0, stream>>>(scratch, out);
  }
}

// Round 15
// 108.335 us; speedup vs baseline: 1.9861x; 1.0078x over previous
//
#include <hip/hip_runtime.h>
#include <math.h>

#define HH 192
#define WW 192
#define CC 64
#define CHW (HH*WW)
#define SS 16
#define NB 12
#define NBLK 144
#define CCH 8            // channels per LDS chunk
#define UROW 22          // union region rows
#define LROW 36          // padded LDS row stride (floats): 4r mod 32 -> uniform bank spread
#define QN 6             // float4 staged per row (24 floats)
#define NSH 49
#define STAGE_N (CCH*UROW*QN)   // 1056 float4 per chunk
// overlay (dwords, after region is dead)
#define PART0 0
#define ASUM0 NSH               // 49

__device__ __forceinline__ int iclamp(int v, int lo, int hi){ return v<lo?lo:(v>hi?hi:v); }

// EX: column-shift class (-3 left, 0 interior, +3 right); OX: compile-time col offset
template<int EX, int OX, int NCH>
__device__ __forceinline__ void run_chunks(
    const float* __restrict__ f1b, const float* __restrict__ f2b,
    float* sm, int tid, int t, int y, int h8, bool active,
    int ys, int xs, int rbase, int ey, int cc0,
    float acc[7], float& asum)
{
  const int cbase4 = (EX == -3) ? 0 : ((EX == 0) ? (xs - 4) : (WW - 24));  // 0 / xs-4 / 168
  const int oyt = iclamp(t + ey, 0, 6);
  const float* ap0 = f1b + (size_t)(ys + y)*WW + xs + h8;
  const int wrow = (y + oyt)*LROW + h8;

  constexpr int OMIN = ((0+EX) < 0 ? 0 : ((0+EX) > 6 ? 6 : (0+EX))) + OX;
  constexpr int OMAX = ((6+EX) < 0 ? 0 : ((6+EX) > 6 ? 6 : (6+EX))) + OX;
  constexpr int NW = OMAX - OMIN + 1;      // <=7 ; OMAX+7 <= 15 fits w[16]

  for (int ch0 = 0; ch0 < NCH; ch0 += CCH) {
    const int cc = cc0 + ch0;
    // ---- stage fm2 union region [cc..cc+7][rbase..+21][cbase4..+23]
    for (int i = tid; i < STAGE_N; i += 256) {
      int ch  = i / (UROW*QN);
      int rem = i - ch*(UROW*QN);
      int r   = rem / QN;
      int q   = rem - r*QN;
      *(float4*)&sm[ch*(UROW*LROW) + r*LROW + 4*q] =
        *(const float4*)(f2b + (size_t)(cc+ch)*CHW + (size_t)(rbase+r)*WW + cbase4 + 4*q);
    }
    __syncthreads();

    if (active) {
#pragma unroll 2
      for (int c = 0; c < CCH; c++) {
        const float* ap = ap0 + (size_t)(cc + c)*CHW;   // fm1 half-row (L1-reused x7)
        float a[8];
        {
          float4 v0 = *(const float4*)(ap + 0);
          float4 v1 = *(const float4*)(ap + 4);
          a[0]=v0.x; a[1]=v0.y; a[2]=v0.z; a[3]=v0.w;
          a[4]=v1.x; a[5]=v1.y; a[6]=v1.z; a[7]=v1.w;
        }
        if (t == 0) {                                   // block a^2 once per (y,h8,c)
          asum = fmaf(a[0],a[0], fmaf(a[1],a[1], fmaf(a[2],a[2], fmaf(a[3],a[3], asum))));
          asum = fmaf(a[4],a[4], fmaf(a[5],a[5], fmaf(a[6],a[6], fmaf(a[7],a[7], asum))));
        }
        const float* wp = sm + c*(UROW*LROW) + wrow;
        float w[16];
#pragma unroll
        for (int j = 0; j < 4; j++) {
          float4 v = *(const float4*)(wp + 4*j);        // ds_read_b128, uniform bank spread
          w[4*j]=v.x; w[4*j+1]=v.y; w[4*j+2]=v.z; w[4*j+3]=v.w;
        }
        // sliding 8-wide w^2 windows, compile-time offsets
        float W[NW];
        {
          float s = 0.f;
#pragma unroll
          for (int x = 0; x < 8; x++) s = fmaf(w[OMIN+x], w[OMIN+x], s);
          W[0] = s;
#pragma unroll
          for (int j = 1; j < NW; j++) {
            s = fmaf(w[OMIN+j+7], w[OMIN+j+7], s);
            s = fmaf(-w[OMIN+j-1], w[OMIN+j-1], s);
            W[j] = s;
          }
        }
#pragma unroll
        for (int u = 0; u < 7; u++) {
          const int o = ((u+EX) < 0 ? 0 : ((u+EX) > 6 ? 6 : (u+EX))) + OX;  // folds
          float s0 = 0.f, s1 = 0.f;
#pragma unroll
          for (int x = 0; x < 8; x += 2) {
            s0 = fmaf(a[x],   w[o+x],   s0);            // 1 FMA per MAC
            s1 = fmaf(a[x+1], w[o+x+1], s1);
          }
          acc[u] = fmaf(-2.f, s0 + s1, acc[u] + W[o-OMIN]);
        }
      }
    }
    __syncthreads();
  }
}

// NZ: channel split; 1D grid, XCD-pinned raster swizzle (b = wg&7 fixed per XCD)
template<int NZ>
__global__ __launch_bounds__(256, 4) void dist_kernel(
    const float* __restrict__ fm1, const float* __restrict__ fm2,
    float* __restrict__ partial)
{
  __shared__ float sm[CCH*UROW*LROW];   // 25,344 B; PART/ASUM overlaid after compute

  const int wg  = blockIdx.x;           // [0, NZ*1152)
  const int z   = (NZ == 2 && wg >= 8*NBLK) ? 1 : 0;
  const int w2  = wg - z*8*NBLK;
  const int b   = w2 & 7;               // batch pinned per XCD
  const int blk = w2 >> 3;              // raster (halo L2 reuse)
  const int by  = blk / NB, bx = blk - by*NB;
  const int ys  = by*SS, xs = bx*SS;
  const int rbase = iclamp(ys-3, 0, HH-UROW);
  const int ey = (ys-3) - rbase;        // in {-3,0,3}
  const int cbase = iclamp(xs-3, 0, WW-UROW);
  const int ex = (xs-3) - cbase;        // -3/0/3

  const int tid = threadIdx.x;
  const int t   = tid >> 5;             // 0..7 ; t<7 active (dh = t-3)
  const int y   = tid & 15;             // consecutive lanes = consecutive rows
  const int h8  = ((tid >> 4) & 1) * 8; // x-half: cols [h8, h8+8)
  const bool active = (t < 7);

  const float* f1b = fm1 + (size_t)b*CC*CHW;
  const float* f2b = fm2 + (size_t)b*CC*CHW;
  const int cc0 = z * (CC/NZ);

  float acc[7];
#pragma unroll
  for (int k = 0; k < 7; k++) acc[k] = 0.f;
  float asum = 0.f;

  if (bx == 0)
    run_chunks<-3,0,CC/NZ>(f1b, f2b, sm, tid, t, y, h8, active, ys, xs, rbase, ey, cc0, acc, asum);
  else if (bx == NB-1)
    run_chunks< 3,2,CC/NZ>(f1b, f2b, sm, tid, t, y, h8, active, ys, xs, rbase, ey, cc0, acc, asum);
  else
    run_chunks< 0,1,CC/NZ>(f1b, f2b, sm, tid, t, y, h8, active, ys, xs, rbase, ey, cc0, acc, asum);

  // ---- overlay merge (region dead after final barrier of run_chunks)
  float* distk = sm;                    // PART[49] at 0, ASUM at 49
#pragma unroll
  for (int u = 0; u < 7; u++) {
    float v = acc[u];
#pragma unroll
    for (int off = 16; off; off >>= 1) v += __shfl_xor(v, off);
    if (active && (tid & 31) == 0) distk[PART0 + t*7 + u] = v;
  }
  {
    float v = asum;                     // t==0 group holds full block a^2
#pragma unroll
    for (int off = 16; off; off >>= 1) v += __shfl_xor(v, off);
    if (tid == 0) distk[ASUM0] = v;
  }
  __syncthreads();

  if constexpr (NZ == 2) {
    if (tid < NSH)
      partial[((size_t)(b*NBLK + blk)*2 + z)*NSH + tid] =
        distk[ASUM0] + distk[PART0 + tid];               // raw z-partial
  } else {
    if (tid < 64) {
      float s = (tid < NSH) ? (distk[ASUM0] + distk[PART0 + tid]) : __builtin_inff();
#pragma unroll
      for (int off = 32; off; off >>= 1) s = fminf(s, __shfl_xor(s, off));
      if (tid == 0) partial[(size_t)b*NBLK + blk] = s;   // raw min
    }
  }
}

template<int NZ>
__global__ void topk_kernel(const float* __restrict__ partial, float* __restrict__ out)
{
  const int b = blockIdx.x;
  const int lane = threadIdx.x;
  const float INF = __builtin_inff();

  float v0 = INF, v1 = INF, v2 = INF;
  if constexpr (NZ == 2) {
#pragma unroll
    for (int i = 0; i < 3; i++) {
      int blk = lane + 64*i;
      if (blk < NBLK) {
        const float* p = partial + (size_t)(b*NBLK + blk)*2*NSH;
        float m = INF;
        for (int k = 0; k < NSH; k++) m = fminf(m, p[k] + p[k+NSH]);
        if (i == 0) v0 = m; else if (i == 1) v1 = m; else v2 = m;
      }
    }
  } else {
    const float* p = partial + (size_t)b*NBLK;
    v0 = p[lane];
    v1 = p[lane + 64];
    v2 = (lane < 16) ? p[lane + 128] : INF;
  }

  float sum = 0.f;
  for (int it = 0; it < 16; ++it) {
    float lm = fminf(v0, fminf(v1, v2));
    float m = lm;
#pragma unroll
    for (int off = 32; off; off >>= 1) m = fminf(m, __shfl_xor(m, off));
    sum += m;
    unsigned long long mask = __ballot(lm == m);
    int leader = __ffsll(mask) - 1;
    if (lane == leader) {
      if (v0 == m)      v0 = INF;
      else if (v1 == m) v1 = INF;
      else              v2 = INF;
    }
  }
  if (lane == 0) out[b] = sum * (1.0f/((float)CC*SS*SS));
}

extern "C" void kernel_launch(void* const* d_in, const int* in_sizes, int n_in,
                              void* d_out, int out_size, void* d_ws, size_t ws_size,
                              hipStream_t stream)
{
  const float* fm1 = (const float*)d_in[0];
  const float* fm2 = (const float*)d_in[1];
  float* out  = (float*)d_out;
  float* scratch = (float*)d_ws;

  const size_t NEED = (size_t)8 * NBLK * 2 * NSH * sizeof(float);  // 451,584 B
  if (ws_size >= NEED) {
    dist_kernel<2><<<2*8*NBLK, 256, 0, stream>>>(fm1, fm2, scratch);
    topk_kernel<2><<<8, 64, 0, stream>>>(scratch, out);
  } else {
    dist_kernel<1><<<8*NBLK, 256, 0, stream>>>(fm1, fm2, scratch);
    topk_kernel<1><<<8, 64, 0, stream>>>(scratch, out);
  }
}

// Round 16
// 106.860 us; speedup vs baseline: 2.0136x; 1.0138x over previous
//
#include <hip/hip_runtime.h>
#include <math.h>

#define HH 192
#define WW 192
#define CC 64
#define CHW (HH*WW)
#define SS 16
#define NB 12
#define NBLK 144
#define CCH 8            // channels per LDS chunk
#define UROW 22          // union region rows
#define LROW 33          // ODD row stride: bank(row) = row mod 32 -> scalar reads <=2-way (free)
#define QN 6             // float4-granule slots per row (24 floats)
#define NSH 49
#define STAGE_N (CCH*UROW*QN)   // 1056 slots per chunk
// overlay (dwords, after region is dead)
#define PART0 0
#define ASUM0 NSH               // 49

__device__ __forceinline__ int iclamp(int v, int lo, int hi){ return v<lo?lo:(v>hi?hi:v); }

// EX: column-shift class (-3 left, 0 interior, +3 right); OX: compile-time col offset
template<int EX, int OX, int NCH>
__device__ __forceinline__ void run_chunks(
    const float* __restrict__ f1b, const float* __restrict__ f2b,
    float* sm, int tid, int t, int y, int h8, bool active,
    int ys, int xs, int rbase, int ey, int cc0,
    float acc[7], float& asum)
{
  const int cbase4 = (EX == -3) ? 0 : ((EX == 0) ? (xs - 4) : (WW - 24));  // 0 / xs-4 / 168
  const int oyt = iclamp(t + ey, 0, 6);
  const float* ap0 = f1b + (size_t)(ys + y)*WW + xs + h8;
  const int wrow = (y + oyt)*LROW + h8;

  constexpr int OMIN = ((0+EX) < 0 ? 0 : ((0+EX) > 6 ? 6 : (0+EX))) + OX;
  constexpr int OMAX = ((6+EX) < 0 ? 0 : ((6+EX) > 6 ? 6 : (6+EX))) + OX;
  constexpr int NW = OMAX - OMIN + 1;      // <=7 ; OMAX+7 <= 15 fits w[16]

  for (int ch0 = 0; ch0 < NCH; ch0 += CCH) {
    const int cc = cc0 + ch0;
    // ---- stage fm2 union region [cc..cc+7][rbase..+21][cbase4..+23]
    // global read b128; LDS store 4 scalars (odd stride forbids 16B casts)
    for (int i = tid; i < STAGE_N; i += 256) {
      int ch  = i / (UROW*QN);
      int rem = i - ch*(UROW*QN);
      int r   = rem / QN;
      int q   = rem - r*QN;
      float4 v = *(const float4*)(f2b + (size_t)(cc+ch)*CHW + (size_t)(rbase+r)*WW + cbase4 + 4*q);
      float* dst = &sm[ch*(UROW*LROW) + r*LROW + 4*q];
      dst[0] = v.x; dst[1] = v.y; dst[2] = v.z; dst[3] = v.w;
    }
    __syncthreads();

    if (active) {
#pragma unroll 2
      for (int c = 0; c < CCH; c++) {
        const float* ap = ap0 + (size_t)(cc + c)*CHW;   // fm1 half-row (L1-reused x7)
        float a[8];
        {
          float4 v0 = *(const float4*)(ap + 0);
          float4 v1 = *(const float4*)(ap + 4);
          a[0]=v0.x; a[1]=v0.y; a[2]=v0.z; a[3]=v0.w;
          a[4]=v1.x; a[5]=v1.y; a[6]=v1.z; a[7]=v1.w;
        }
        if (t == 0) {                                   // block a^2 once per (y,h8,c)
          asum = fmaf(a[0],a[0], fmaf(a[1],a[1], fmaf(a[2],a[2], fmaf(a[3],a[3], asum))));
          asum = fmaf(a[4],a[4], fmaf(a[5],a[5], fmaf(a[6],a[6], fmaf(a[7],a[7], asum))));
        }
        const float* wp = sm + c*(UROW*LROW) + wrow;
        float w[16];
#pragma unroll
        for (int k = 0; k < 16; k++) w[k] = wp[k];      // scalar b32, banks = row+k: <=2-way
        // sliding 8-wide w^2 windows, compile-time offsets
        float W[NW];
        {
          float s = 0.f;
#pragma unroll
          for (int x = 0; x < 8; x++) s = fmaf(w[OMIN+x], w[OMIN+x], s);
          W[0] = s;
#pragma unroll
          for (int j = 1; j < NW; j++) {
            s = fmaf(w[OMIN+j+7], w[OMIN+j+7], s);
            s = fmaf(-w[OMIN+j-1], w[OMIN+j-1], s);
            W[j] = s;
          }
        }
#pragma unroll
        for (int u = 0; u < 7; u++) {
          const int o = ((u+EX) < 0 ? 0 : ((u+EX) > 6 ? 6 : (u+EX))) + OX;  // folds
          float s0 = 0.f, s1 = 0.f;
#pragma unroll
          for (int x = 0; x < 8; x += 2) {
            s0 = fmaf(a[x],   w[o+x],   s0);            // 1 FMA per MAC
            s1 = fmaf(a[x+1], w[o+x+1], s1);
          }
          acc[u] = fmaf(-2.f, s0 + s1, acc[u] + W[o-OMIN]);
        }
      }
    }
    __syncthreads();
  }
}

// NZ: channel split; 1D grid, XCD-pinned raster swizzle (b = wg&7 fixed per XCD)
template<int NZ>
__global__ __launch_bounds__(256, 4) void dist_kernel(
    const float* __restrict__ fm1, const float* __restrict__ fm2,
    float* __restrict__ partial)
{
  __shared__ float sm[CCH*UROW*LROW];   // 23,232 B; PART/ASUM overlaid after compute

  const int wg  = blockIdx.x;           // [0, NZ*1152)
  const int z   = (NZ == 2 && wg >= 8*NBLK) ? 1 : 0;
  const int w2  = wg - z*8*NBLK;
  const int b   = w2 & 7;               // batch pinned per XCD
  const int blk = w2 >> 3;              // raster (halo L2 reuse)
  const int by  = blk / NB, bx = blk - by*NB;
  const int ys  = by*SS, xs = bx*SS;
  const int rbase = iclamp(ys-3, 0, HH-UROW);
  const int ey = (ys-3) - rbase;        // in {-3,0,3}
  const int cbase = iclamp(xs-3, 0, WW-UROW);
  const int ex = (xs-3) - cbase;        // -3/0/3

  const int tid = threadIdx.x;
  const int t   = tid >> 5;             // 0..7 ; t<7 active (dh = t-3)
  const int y   = tid & 15;             // consecutive lanes = consecutive rows
  const int h8  = ((tid >> 4) & 1) * 8; // x-half: cols [h8, h8+8)
  const bool active = (t < 7);

  const float* f1b = fm1 + (size_t)b*CC*CHW;
  const float* f2b = fm2 + (size_t)b*CC*CHW;
  const int cc0 = z * (CC/NZ);

  float acc[7];
#pragma unroll
  for (int k = 0; k < 7; k++) acc[k] = 0.f;
  float asum = 0.f;

  if (bx == 0)
    run_chunks<-3,0,CC/NZ>(f1b, f2b, sm, tid, t, y, h8, active, ys, xs, rbase, ey, cc0, acc, asum);
  else if (bx == NB-1)
    run_chunks< 3,2,CC/NZ>(f1b, f2b, sm, tid, t, y, h8, active, ys, xs, rbase, ey, cc0, acc, asum);
  else
    run_chunks< 0,1,CC/NZ>(f1b, f2b, sm, tid, t, y, h8, active, ys, xs, rbase, ey, cc0, acc, asum);

  // ---- overlay merge (region dead after final barrier of run_chunks)
  float* distk = sm;                    // PART[49] at 0, ASUM at 49
#pragma unroll
  for (int u = 0; u < 7; u++) {
    float v = acc[u];
#pragma unroll
    for (int off = 16; off; off >>= 1) v += __shfl_xor(v, off);
    if (active && (tid & 31) == 0) distk[PART0 + t*7 + u] = v;
  }
  {
    float v = asum;                     // t==0 group holds full block a^2
#pragma unroll
    for (int off = 16; off; off >>= 1) v += __shfl_xor(v, off);
    if (tid == 0) distk[ASUM0] = v;
  }
  __syncthreads();

  if constexpr (NZ == 2) {
    if (tid < NSH)
      partial[((size_t)(b*NBLK + blk)*2 + z)*NSH + tid] =
        distk[ASUM0] + distk[PART0 + tid];               // raw z-partial
  } else {
    if (tid < 64) {
      float s = (tid < NSH) ? (distk[ASUM0] + distk[PART0 + tid]) : __builtin_inff();
#pragma unroll
      for (int off = 32; off; off >>= 1) s = fminf(s, __shfl_xor(s, off));
      if (tid == 0) partial[(size_t)b*NBLK + blk] = s;   // raw min
    }
  }
}

template<int NZ>
__global__ void topk_kernel(const float* __restrict__ partial, float* __restrict__ out)
{
  const int b = blockIdx.x;
  const int lane = threadIdx.x;
  const float INF = __builtin_inff();

  float v0 = INF, v1 = INF, v2 = INF;
  if constexpr (NZ == 2) {
#pragma unroll
    for (int i = 0; i < 3; i++) {
      int blk = lane + 64*i;
      if (blk < NBLK) {
        const float* p = partial + (size_t)(b*NBLK + blk)*2*NSH;
        float m = INF;
        for (int k = 0; k < NSH; k++) m = fminf(m, p[k] + p[k+NSH]);
        if (i == 0) v0 = m; else if (i == 1) v1 = m; else v2 = m;
      }
    }
  } else {
    const float* p = partial + (size_t)b*NBLK;
    v0 = p[lane];
    v1 = p[lane + 64];
    v2 = (lane < 16) ? p[lane + 128] : INF;
  }

  float sum = 0.f;
  for (int it = 0; it < 16; ++it) {
    float lm = fminf(v0, fminf(v1, v2));
    float m = lm;
#pragma unroll
    for (int off = 32; off; off >>= 1) m = fminf(m, __shfl_xor(m, off));
    sum += m;
    unsigned long long mask = __ballot(lm == m);
    int leader = __ffsll(mask) - 1;
    if (lane == leader) {
      if (v0 == m)      v0 = INF;
      else if (v1 == m) v1 = INF;
      else              v2 = INF;
    }
  }
  if (lane == 0) out[b] = sum * (1.0f/((float)CC*SS*SS));
}

extern "C" void kernel_launch(void* const* d_in, const int* in_sizes, int n_in,
                              void* d_out, int out_size, void* d_ws, size_t ws_size,
                              hipStream_t stream)
{
  const float* fm1 = (const float*)d_in[0];
  const float* fm2 = (const float*)d_in[1];
  float* out  = (float*)d_out;
  float* scratch = (float*)d_ws;

  const size_t NEED = (size_t)8 * NBLK * 2 * NSH * sizeof(float);  // 451,584 B
  if (ws_size >= NEED) {
    dist_kernel<2><<<2*8*NBLK, 256, 0, stream>>>(fm1, fm2, scratch);
    topk_kernel<2><<<8, 64, 0, stream>>>(scratch, out);
  } else {
    dist_kernel<1><<<8*NBLK, 256, 0, stream>>>(fm1, fm2, scratch);
    topk_kernel<1><<<8, 64, 0, stream>>>(scratch, out);
  }
}